// Round 4
// baseline (473.288 us; speedup 1.0000x reference)
//
#include <hip/hip_runtime.h>
#include <hip/hip_bf16.h>

typedef __bf16 bf16_t;
typedef __bf16 bf16x8 __attribute__((ext_vector_type(8)));
typedef __bf16 bf16x4 __attribute__((ext_vector_type(4)));
typedef float f32x16 __attribute__((ext_vector_type(16)));
typedef unsigned int u32;
typedef const __attribute__((address_space(1))) u32* gptr_t;
typedef __attribute__((address_space(3))) u32* lptr_t;

static constexpr int Bb = 16, Ss = 1024, Hh = 768;
static constexpr int MTOK = Bb * Ss; // 16384

// ---- merged conversion: x -> bf16, 5 weights -> bf16 slab, pack bqkv ----
__global__ __launch_bounds__(256) void cvt_all(
    const float* __restrict__ x,
    const float* __restrict__ w0, const float* __restrict__ w1,
    const float* __restrict__ w2, const float* __restrict__ w3,
    const float* __restrict__ w4,
    const float* __restrict__ bq, const float* __restrict__ bk,
    const float* __restrict__ bv,
    bf16_t* __restrict__ xb, bf16_t* __restrict__ wdst, float* __restrict__ bdst)
{
    int bx = blockIdx.x;
    if (bx < 12288) {
        int i = bx * 256 + threadIdx.x;
        float4 v = ((const float4*)x)[i];
        bf16x4 o = { (bf16_t)v.x, (bf16_t)v.y, (bf16_t)v.z, (bf16_t)v.w };
        ((bf16x4*)xb)[i] = o;
    } else if (bx < 15168) {
        int b2 = bx - 12288;
        int seg = b2 / 576;
        const float* src = seg == 0 ? w0 : seg == 1 ? w1 : seg == 2 ? w2 : seg == 3 ? w3 : w4;
        int i = (b2 % 576) * 256 + threadIdx.x;
        float4 v = ((const float4*)src)[i];
        bf16x4 o = { (bf16_t)v.x, (bf16_t)v.y, (bf16_t)v.z, (bf16_t)v.w };
        ((bf16x4*)(wdst + (long)seg * 589824))[i] = o;
    } else {
        int i = (bx - 15168) * 256 + threadIdx.x;
        if (i < 2304)
            bdst[i] = i < 768 ? bq[i] : i < 1536 ? bk[i - 768] : bv[i - 1536];
    }
}

// ---------------- async global->LDS 16B ----------------
__device__ __forceinline__ void async_cp16(const void* g, void* l)
{
    __builtin_amdgcn_global_load_lds((gptr_t)g, (lptr_t)l, 16, 0, 0);
}

enum { EG_RELU_BIAS_B16 = 0, EG_QKV = 1, EG_SCORE_T = 2, EG_B16 = 3, EG_FINAL = 4 };

// C = epi(A * B^T); A:[M,K] k-contig, B:[N,K] k-contig, bf16 in, fp32 accum.
// 128x128 tile, BK=32, 4 waves (2x2), each wave 2x2 of mfma_f32_32x32x16_bf16.
// LDS k-major layout: 16-row group g, elem = g*512 + (k/8)*128 + (row%16)*8
// -> fragment ds_read_b128 is 2-way bank aliased (free), staging DMA sequential.
template <int EPI>
__global__ __launch_bounds__(256) void mfma_gemm(
    const bf16_t* __restrict__ A, const bf16_t* __restrict__ B,
    const float* __restrict__ bias, const bf16_t* __restrict__ resid,
    const int* __restrict__ mask, void* __restrict__ Cout,
    bf16_t* __restrict__ out2, bf16_t* __restrict__ out3,
    int K, int lda, int ldb, int ldc,
    long sA, long sB, long sC, float scale)
{
    __shared__ bf16_t Asl[128 * 32];
    __shared__ bf16_t Bsl[128 * 32];

    const int tid = threadIdx.x;
    const int wid = tid >> 6;
    const int lane = tid & 63;
    const int wm = wid & 1, wn = wid >> 1;
    const int m0 = blockIdx.y * 128;
    const int n0 = blockIdx.x * 128;
    const int bz = blockIdx.z;

    const bf16_t* Ab = A + (long)bz * sA;
    const bf16_t* Bp = B + (long)bz * sB;

    // staging: lane l of wave w loads 16B from row w*16+(l&15), kcol (l>>4)*8
    const int srow = (wid << 4) + (lane & 15);
    const int scol = (lane >> 4) << 3;

    const bf16_t* pa0 = Ab + (long)(m0 + srow) * lda + scol;
    const bf16_t* pa1 = Ab + (long)(m0 + 64 + srow) * lda + scol;
    const bf16_t* pb0 = Bp + (long)(n0 + srow) * ldb + scol;
    const bf16_t* pb1 = Bp + (long)(n0 + 64 + srow) * ldb + scol;

    bf16_t* la = &Asl[wid << 9];   // wave-uniform LDS bases (group = wid)
    bf16_t* lb = &Bsl[wid << 9];

    // fragment indices: m(or n) = gh*16 + r15 within 32-row tile; k-half = kh
    const int r15 = lane & 15;
    const int gh = (lane >> 4) & 1;
    const int kh = lane >> 5;

    f32x16 acc[2][2] = {};

    for (int k0 = 0; k0 < K; k0 += 32) {
        async_cp16(pa0 + k0, la);
        async_cp16(pa1 + k0, la + 2048);
        async_cp16(pb0 + k0, lb);
        async_cp16(pb1 + k0, lb + 2048);
        __syncthreads();

        bf16x8 af[2][2], bfr[2][2];
#pragma unroll
        for (int mt = 0; mt < 2; mt++)
#pragma unroll
            for (int s = 0; s < 2; s++)
                af[mt][s] = *(const bf16x8*)
                    &Asl[((wm << 2) + (mt << 1) + gh) * 512 + ((s << 1) + kh) * 128 + (r15 << 3)];
#pragma unroll
        for (int nt = 0; nt < 2; nt++)
#pragma unroll
            for (int s = 0; s < 2; s++)
                bfr[nt][s] = *(const bf16x8*)
                    &Bsl[((wn << 2) + (nt << 1) + gh) * 512 + ((s << 1) + kh) * 128 + (r15 << 3)];
#pragma unroll
        for (int s = 0; s < 2; s++)
#pragma unroll
            for (int mt = 0; mt < 2; mt++)
#pragma unroll
                for (int nt = 0; nt < 2; nt++)
                    acc[mt][nt] = __builtin_amdgcn_mfma_f32_32x32x16_bf16(
                        af[mt][s], bfr[nt][s], acc[mt][nt], 0, 0, 0);
        __syncthreads();
    }

    // epilogue — 32x32 C/D layout: col = lane&31, row = (e&3) + 8*(e>>2) + 4*(lane>>5)
    const int mb_ = m0 + (wm << 6);
    const int nb_ = n0 + (wn << 6);
    const int l31 = lane & 31;
    const int kh4 = kh << 2;

    if constexpr (EPI == EG_QKV) {
        float bj[2];
#pragma unroll
        for (int nt = 0; nt < 2; nt++) bj[nt] = bias[nb_ + (nt << 5) + l31];
        if (nb_ < 1536) {
            bf16_t* C = (nb_ < 768) ? (bf16_t*)Cout : out2;
            const int cb = (nb_ < 768) ? nb_ : nb_ - 768;
#pragma unroll
            for (int mt = 0; mt < 2; mt++)
#pragma unroll
                for (int nt = 0; nt < 2; nt++)
#pragma unroll
                    for (int e = 0; e < 16; e++) {
                        int row = mb_ + (mt << 5) + ((e >> 2) << 3) + kh4 + (e & 3);
                        int col = cb + (nt << 5) + l31;
                        C[(long)row * Hh + col] = (bf16_t)fmaxf(acc[mt][nt][e] + bj[nt], 0.f);
                    }
        } else {
#pragma unroll
            for (int mt = 0; mt < 2; mt++)
#pragma unroll
                for (int q = 0; q < 4; q++) {
                    const int sAbs = mb_ + (mt << 5) + (q << 3) + kh4;
                    const int b = sAbs >> 10;
                    const int sl = sAbs & 1023;
#pragma unroll
                    for (int nt = 0; nt < 2; nt++) {
                        const int col = nb_ - 1536 + (nt << 5) + l31;
                        bf16x4 o = { (bf16_t)(acc[mt][nt][q * 4 + 0] + bj[nt]),
                                     (bf16_t)(acc[mt][nt][q * 4 + 1] + bj[nt]),
                                     (bf16_t)(acc[mt][nt][q * 4 + 2] + bj[nt]),
                                     (bf16_t)(acc[mt][nt][q * 4 + 3] + bj[nt]) };
                        *(bf16x4*)&out3[((long)b * Hh + col) * Ss + sl] = o;
                    }
                }
        }
    } else if constexpr (EPI == EG_SCORE_T) {
        // computed T = k·q^T; rows = keys, cols = queries; store S = T^T (bf16)
        bf16_t* C = (bf16_t*)Cout + (long)bz * sC;
        const int* mk = mask + bz * Ss;
        int mq[2];
#pragma unroll
        for (int nt = 0; nt < 2; nt++) mq[nt] = mk[nb_ + (nt << 5) + l31];
#pragma unroll
        for (int mt = 0; mt < 2; mt++)
#pragma unroll
            for (int q = 0; q < 4; q++) {
                const int kb4 = mb_ + (mt << 5) + (q << 3) + kh4;
                int4 mkey = *(const int4*)&mk[kb4];
#pragma unroll
                for (int nt = 0; nt < 2; nt++) {
                    const int qrow = nb_ + (nt << 5) + l31;
                    bf16x4 o;
                    o[0] = (mkey.x & mq[nt]) ? (bf16_t)(acc[mt][nt][q * 4 + 0] * scale) : (bf16_t)(-1e12f);
                    o[1] = (mkey.y & mq[nt]) ? (bf16_t)(acc[mt][nt][q * 4 + 1] * scale) : (bf16_t)(-1e12f);
                    o[2] = (mkey.z & mq[nt]) ? (bf16_t)(acc[mt][nt][q * 4 + 2] * scale) : (bf16_t)(-1e12f);
                    o[3] = (mkey.w & mq[nt]) ? (bf16_t)(acc[mt][nt][q * 4 + 3] * scale) : (bf16_t)(-1e12f);
                    *(bf16x4*)&C[(long)qrow * ldc + kb4] = o;
                }
            }
    } else if constexpr (EPI == EG_FINAL) {
        float* C = (float*)Cout;
        float bj[2];
#pragma unroll
        for (int nt = 0; nt < 2; nt++) bj[nt] = bias[nb_ + (nt << 5) + l31];
#pragma unroll
        for (int mt = 0; mt < 2; mt++)
#pragma unroll
            for (int nt = 0; nt < 2; nt++)
#pragma unroll
                for (int e = 0; e < 16; e++) {
                    int row = mb_ + (mt << 5) + ((e >> 2) << 3) + kh4 + (e & 3);
                    int col = nb_ + (nt << 5) + l31;
                    C[(long)row * ldc + col] =
                        acc[mt][nt][e] + bj[nt] + (float)resid[(long)row * ldc + col];
                }
    } else {
        bf16_t* C = (bf16_t*)Cout + (long)bz * sC;
        float bj[2] = {0.f, 0.f};
        if constexpr (EPI == EG_RELU_BIAS_B16) {
#pragma unroll
            for (int nt = 0; nt < 2; nt++) bj[nt] = bias[nb_ + (nt << 5) + l31];
        }
#pragma unroll
        for (int mt = 0; mt < 2; mt++)
#pragma unroll
            for (int nt = 0; nt < 2; nt++)
#pragma unroll
                for (int e = 0; e < 16; e++) {
                    int row = mb_ + (mt << 5) + ((e >> 2) << 3) + kh4 + (e & 3);
                    int col = nb_ + (nt << 5) + l31;
                    float v = acc[mt][nt][e] + bj[nt];
                    if constexpr (EPI == EG_RELU_BIAS_B16) v = fmaxf(v, 0.f);
                    C[(long)row * ldc + col] = (bf16_t)v;
                }
    }
}

// ---------------- masked softmax, bf16 in / bf16 out (in place) ----------------
__global__ __launch_bounds__(256) void softmax_rows(bf16_t* __restrict__ S_,
                                                    const int* __restrict__ mask)
{
    const int row = blockIdx.x;
    const int b = row >> 10;
    const int s = row & 1023;
    bf16_t* p = S_ + (long)row * Ss;
    const int* mk = mask + b * Ss;
    const int t = threadIdx.x;
    const int t0 = t << 2;

    bf16x4 v4 = *(const bf16x4*)&p[t0];
    float v0 = (float)v4[0], v1 = (float)v4[1], v2 = (float)v4[2], v3 = (float)v4[3];

    float mx = fmaxf(fmaxf(v0, v1), fmaxf(v2, v3));
#pragma unroll
    for (int off = 32; off; off >>= 1) mx = fmaxf(mx, __shfl_down(mx, off, 64));
    __shared__ float redm[4], reds[4];
    if ((t & 63) == 0) redm[t >> 6] = mx;
    __syncthreads();
    mx = fmaxf(fmaxf(redm[0], redm[1]), fmaxf(redm[2], redm[3]));

    float e0 = __expf(v0 - mx), e1 = __expf(v1 - mx);
    float e2 = __expf(v2 - mx), e3 = __expf(v3 - mx);
    float sm = e0 + e1 + e2 + e3;
#pragma unroll
    for (int off = 32; off; off >>= 1) sm += __shfl_down(sm, off, 64);
    if ((t & 63) == 0) reds[t >> 6] = sm;
    __syncthreads();
    sm = reds[0] + reds[1] + reds[2] + reds[3];

    const float inv = 1.f / sm;
    const float fs = (float)mk[s];
    bf16x4 o = { (bf16_t)(e0 * inv * fs * (float)mk[t0 + 0]),
                 (bf16_t)(e1 * inv * fs * (float)mk[t0 + 1]),
                 (bf16_t)(e2 * inv * fs * (float)mk[t0 + 2]),
                 (bf16_t)(e3 * inv * fs * (float)mk[t0 + 3]) };
    *(bf16x4*)&p[t0] = o;
}

extern "C" void kernel_launch(void* const* d_in, const int* in_sizes, int n_in,
                              void* d_out, int out_size, void* d_ws, size_t ws_size,
                              hipStream_t stream)
{
    const float* x  = (const float*)d_in[0];
    const int* mask = (const int*)d_in[1];
    const float* Wq = (const float*)d_in[2];
    const float* bq = (const float*)d_in[3];
    const float* Wk = (const float*)d_in[4];
    const float* bk = (const float*)d_in[5];
    const float* Wv = (const float*)d_in[6];
    const float* bv = (const float*)d_in[7];
    const float* W1 = (const float*)d_in[8];
    const float* b1 = (const float*)d_in[9];
    const float* W2 = (const float*)d_in[10];
    const float* b2 = (const float*)d_in[11];
    float* out = (float*)d_out;

    // workspace layout (~140 MB)
    char* w = (char*)d_ws;
    bf16_t* xb   = (bf16_t*)(w + 0);            // [16384,768], reused as ctx
    bf16_t* qb   = (bf16_t*)(w + 25165824);     // reused as h1
    bf16_t* kb   = (bf16_t*)(w + 50331648);
    bf16_t* vT   = (bf16_t*)(w + 75497472);     // [16,768,1024]
    bf16_t* sc   = (bf16_t*)(w + 100663296);    // [16,1024,1024] bf16
    bf16_t* wqkv = (bf16_t*)(w + 134217728);    // [2304,768] = Wq|Wk|Wv
    bf16_t* w1b  = (bf16_t*)(w + 137756672);
    bf16_t* w2b  = (bf16_t*)(w + 138936320);
    float*  bqkv = (float*) (w + 140115968);    // [2304]
    bf16_t* ctx  = xb;
    bf16_t* h1   = qb;

    const float inv_sqrt_h = 0.036084391824351615f; // 1/sqrt(768)

    cvt_all<<<15177, 256, 0, stream>>>(x, Wq, Wk, Wv, W1, W2, bq, bk, bv, xb, wqkv, bqkv);

    dim3 blk(256);

    // fused q|k|vT = epi(x · [Wq|Wk|Wv]^T + bqkv)
    mfma_gemm<EG_QKV><<<dim3(18, 128, 1), blk, 0, stream>>>(
        xb, wqkv, bqkv, nullptr, nullptr, qb, kb, vT,
        768, 768, 768, 768, 0, 0, 0, 1.f);

    // sc[q][k] = (k·q^T)^T * scale with mask penalty, bf16
    mfma_gemm<EG_SCORE_T><<<dim3(8, 8, 16), blk, 0, stream>>>(
        kb, qb, nullptr, nullptr, mask, sc, nullptr, nullptr,
        768, 768, 768, 1024, 786432, 786432, 1048576, inv_sqrt_h);

    // masked softmax in place (bf16)
    softmax_rows<<<dim3(MTOK), blk, 0, stream>>>(sc, mask);

    // ctx = sc · vT^T
    mfma_gemm<EG_B16><<<dim3(6, 8, 16), blk, 0, stream>>>(
        sc, vT, nullptr, nullptr, nullptr, ctx, nullptr, nullptr,
        1024, 1024, 1024, 768, 1048576, 786432, 786432, 1.f);

    // h1 = relu(ctx · W1^T + b1)
    mfma_gemm<EG_RELU_BIAS_B16><<<dim3(6, 128, 1), blk, 0, stream>>>(
        ctx, w1b, b1, nullptr, nullptr, h1, nullptr, nullptr,
        768, 768, 768, 768, 0, 0, 0, 1.f);

    // out = h1 · W2^T + b2 + ctx  (fp32)
    mfma_gemm<EG_FINAL><<<dim3(6, 128, 1), blk, 0, stream>>>(
        h1, w2b, b2, ctx, nullptr, out, nullptr, nullptr,
        768, 768, 768, 768, 0, 0, 0, 1.f);
}